// Round 1
// baseline (127.576 us; speedup 1.0000x reference)
//
#include <hip/hip_runtime.h>

// LinearAttention: q,k,v fp32 [4,16,4096,64]; out = (Q' (K'^T V)) / (Q'.k_sum + eps)
// where X' = elu(X)+1. Two-pass: (1) reduce K'^T V and k_sum per (b,h) into ws,
// (2) stream Q, apply kv_agg and normalize.

#define EPS_LA 1e-6f

constexpr int BH = 64;        // batch*heads
constexpr int SEQ = 4096;
constexpr int DIM = 64;
constexpr int NCHUNK = 16;    // s-chunks per bh in pass 1
constexpr int CHUNK = SEQ / NCHUNK;  // 256 rows
constexpr int TS = 32;        // staged rows per LDS subtile
constexpr int WS_STRIDE = DIM * DIM + DIM;  // kv[64][64] + ksum[64] per bh

__device__ __forceinline__ float elu1(float x) {
    // elu(x)+1 = x+1 (x>0), exp(x) (x<=0)
    return x > 0.f ? x + 1.f : __expf(x);
}

__global__ __launch_bounds__(256) void kv_reduce_kernel(
    const float* __restrict__ K, const float* __restrict__ V,
    float* __restrict__ ws) {
    const int bh = blockIdx.y;
    const int chunk = blockIdx.x;
    const float* Kb = K + ((size_t)bh * SEQ + (size_t)chunk * CHUNK) * DIM;
    const float* Vb = V + ((size_t)bh * SEQ + (size_t)chunk * CHUNK) * DIM;

    __shared__ float kS[TS][DIM];
    __shared__ float vS[TS][DIM];

    const int t = threadIdx.x;
    const int tr = t >> 4;   // 0..15 -> rows (d) 4*tr..4*tr+3 of kv_agg
    const int tc = t & 15;   // 0..15 -> cols (e) 4*tc..4*tc+3

    float acc[4][4] = {{0.f}};
    float ksum = 0.f;

    for (int s0 = 0; s0 < CHUNK; s0 += TS) {
        __syncthreads();
        // stage TS x 64 of k' (elu applied) and v: 2048 floats each, 2 float4/thread
        #pragma unroll
        for (int i = 0; i < 2; ++i) {
            const int idx = (i * 256 + t) * 4;
            const int r = idx >> 6, c = idx & 63;
            float4 kk = *(const float4*)(Kb + (size_t)(s0 + r) * DIM + c);
            kk.x = elu1(kk.x); kk.y = elu1(kk.y);
            kk.z = elu1(kk.z); kk.w = elu1(kk.w);
            *(float4*)&kS[r][c] = kk;
            *(float4*)&vS[r][c] = *(const float4*)(Vb + (size_t)(s0 + r) * DIM + c);
        }
        __syncthreads();
        // ksum partial: thread t (<64) accumulates column t
        if (t < DIM) {
            #pragma unroll
            for (int s = 0; s < TS; ++s) ksum += kS[s][t];
        }
        // outer-product accumulation: acc[i][j] += k'[s][4tr+i] * v[s][4tc+j]
        #pragma unroll
        for (int s = 0; s < TS; ++s) {
            const float4 kk = *(const float4*)&kS[s][tr * 4];
            const float4 vv = *(const float4*)&vS[s][tc * 4];
            acc[0][0] += kk.x * vv.x; acc[0][1] += kk.x * vv.y;
            acc[0][2] += kk.x * vv.z; acc[0][3] += kk.x * vv.w;
            acc[1][0] += kk.y * vv.x; acc[1][1] += kk.y * vv.y;
            acc[1][2] += kk.y * vv.z; acc[1][3] += kk.y * vv.w;
            acc[2][0] += kk.z * vv.x; acc[2][1] += kk.z * vv.y;
            acc[2][2] += kk.z * vv.z; acc[2][3] += kk.z * vv.w;
            acc[3][0] += kk.w * vv.x; acc[3][1] += kk.w * vv.y;
            acc[3][2] += kk.w * vv.z; acc[3][3] += kk.w * vv.w;
        }
    }

    float* w = ws + (size_t)bh * WS_STRIDE;
    #pragma unroll
    for (int i = 0; i < 4; ++i) {
        #pragma unroll
        for (int j = 0; j < 4; ++j) {
            atomicAdd(&w[(size_t)(tr * 4 + i) * DIM + tc * 4 + j], acc[i][j]);
        }
    }
    if (t < DIM) atomicAdd(&w[DIM * DIM + t], ksum);
}

__global__ __launch_bounds__(256) void out_kernel(
    const float* __restrict__ Q, const float* __restrict__ ws,
    float* __restrict__ out) {
    const int bh = blockIdx.y;
    const int rb = blockIdx.x;  // 64-row block
    const float* Qb = Q + ((size_t)bh * SEQ + (size_t)rb * 64) * DIM;
    float* Ob = out + ((size_t)bh * SEQ + (size_t)rb * 64) * DIM;
    const float* w = ws + (size_t)bh * WS_STRIDE;

    // qT2[d][swizzled row]: stores q'[row][d] at [d][(chunk^(d&15))*4 + (row&3)],
    // chunk = row>>2. Keeps transpose stores AND float4 reads conflict-free.
    __shared__ float qT2[DIM][DIM];
    __shared__ float kvS[DIM][DIM];
    __shared__ float ksumS[DIM];
    __shared__ float denomS[64];

    const int t = threadIdx.x;
    const int tr = t >> 4;   // row chunk 0..15 -> rows 4tr..4tr+3
    const int tc = t & 15;   // col chunk 0..15 -> cols 4tc..4tc+3

    // load kv_agg (4096 floats)
    #pragma unroll
    for (int i = 0; i < 4; ++i) {
        const int idx = (i * 256 + t) * 4;
        *(float4*)&kvS[idx >> 6][idx & 63] = *(const float4*)(w + idx);
    }
    if (t < DIM) ksumS[t] = w[DIM * DIM + t];

    // load q block 64x64, elu+1, transpose into swizzled qT2
    {
        const int r0 = tr * 4, c0 = tc * 4;
        float4 ql[4];
        #pragma unroll
        for (int i = 0; i < 4; ++i) {
            float4 qq = *(const float4*)(Qb + (size_t)(r0 + i) * DIM + c0);
            qq.x = elu1(qq.x); qq.y = elu1(qq.y);
            qq.z = elu1(qq.z); qq.w = elu1(qq.w);
            ql[i] = qq;
        }
        #pragma unroll
        for (int j = 0; j < 4; ++j) {
            const int d = c0 + j;
            float4 col;
            col.x = (&ql[0].x)[j]; col.y = (&ql[1].x)[j];
            col.z = (&ql[2].x)[j]; col.w = (&ql[3].x)[j];
            *(float4*)&qT2[d][(tr ^ (d & 15)) * 4] = col;
        }
    }
    __syncthreads();

    // per-row denom = q'[row] . ksum + eps  (row = t for t<64)
    if (t < 64) {
        const int chk = t >> 2, lo = t & 3;
        float dsum = 0.f;
        #pragma unroll
        for (int d = 0; d < DIM; ++d) {
            dsum += qT2[d][(chk ^ (d & 15)) * 4 + lo] * ksumS[d];
        }
        denomS[t] = dsum + EPS_LA;
    }

    // num: acc[i][j] = sum_d q'[4tr+i][d] * kv[d][4tc+j]
    float acc[4][4] = {{0.f}};
    #pragma unroll
    for (int d = 0; d < DIM; ++d) {
        const float4 qv = *(const float4*)&qT2[d][(tr ^ (d & 15)) * 4];
        const float4 kv = *(const float4*)&kvS[d][tc * 4];
        acc[0][0] += qv.x * kv.x; acc[0][1] += qv.x * kv.y;
        acc[0][2] += qv.x * kv.z; acc[0][3] += qv.x * kv.w;
        acc[1][0] += qv.y * kv.x; acc[1][1] += qv.y * kv.y;
        acc[1][2] += qv.y * kv.z; acc[1][3] += qv.y * kv.w;
        acc[2][0] += qv.z * kv.x; acc[2][1] += qv.z * kv.y;
        acc[2][2] += qv.z * kv.z; acc[2][3] += qv.z * kv.w;
        acc[3][0] += qv.w * kv.x; acc[3][1] += qv.w * kv.y;
        acc[3][2] += qv.w * kv.z; acc[3][3] += qv.w * kv.w;
    }
    __syncthreads();

    #pragma unroll
    for (int i = 0; i < 4; ++i) {
        const float inv = 1.f / denomS[tr * 4 + i];
        float4 o;
        o.x = acc[i][0] * inv; o.y = acc[i][1] * inv;
        o.z = acc[i][2] * inv; o.w = acc[i][3] * inv;
        *(float4*)(Ob + (size_t)(tr * 4 + i) * DIM + tc * 4) = o;
    }
}

extern "C" void kernel_launch(void* const* d_in, const int* in_sizes, int n_in,
                              void* d_out, int out_size, void* d_ws, size_t ws_size,
                              hipStream_t stream) {
    const float* q = (const float*)d_in[0];
    const float* k = (const float*)d_in[1];
    const float* v = (const float*)d_in[2];
    float* out = (float*)d_out;
    float* ws = (float*)d_ws;

    // zero the kv_agg/ksum accumulator region (deterministic start each call)
    hipMemsetAsync(ws, 0, (size_t)BH * WS_STRIDE * sizeof(float), stream);

    dim3 blk(256);
    dim3 g1(NCHUNK, BH);
    hipLaunchKernelGGL(kv_reduce_kernel, g1, blk, 0, stream, k, v, ws);
    dim3 g2(SEQ / 64, BH);
    hipLaunchKernelGGL(out_kernel, g2, blk, 0, stream, q, ws, out);
}

// Round 2
// 105.322 us; speedup vs baseline: 1.2113x; 1.2113x over previous
//
#include <hip/hip_runtime.h>

// LinearAttention: q,k,v fp32 [4,16,4096,64]; out = (Q' (K'^T V)) / (Q'.k_sum + eps)
// where X' = elu(X)+1.
// Pass 1: kv_reduce2 — per-(bh, 128-row chunk) partial K'^T V + colsum(K'), written
//         to distinct ws slots (no atomics). Register-prefetched halves hide latency.
// Pass 1b: reduce_partials — fold 32 partials -> final [bh][4160].
// Pass 2: out_kernel — stream Q, apply kv_agg, normalize.
// Fallback: if ws too small for partials, atomic accumulation (memset + atomicAdd).

#define EPS_LA 1e-6f

constexpr int BH = 64;        // batch*heads
constexpr int SEQ = 4096;
constexpr int DIM = 64;
constexpr int NCHUNK2 = 32;   // chunks per bh in pass 1
constexpr int ROWS = SEQ / NCHUNK2;          // 128 rows per block
constexpr int KVELEM = DIM * DIM + DIM;      // kv[64][64] + ksum[64] = 4160

__device__ __forceinline__ float elu1(float x) {
    return x > 0.f ? x + 1.f : __expf(x);
}

template<bool ATOMIC>
__global__ __launch_bounds__(256) void kv_reduce2_kernel(
    const float* __restrict__ K, const float* __restrict__ V,
    float* __restrict__ dst) {
    const int bh = blockIdx.y;
    const int chunk = blockIdx.x;
    const float* Kb = K + ((size_t)bh * SEQ + (size_t)chunk * ROWS) * DIM;
    const float* Vb = V + ((size_t)bh * SEQ + (size_t)chunk * ROWS) * DIM;

    __shared__ float kS[64][64];
    __shared__ float vS[64][64];

    const int t = threadIdx.x;
    const int tr = t >> 4;          // 0..15: output rows 4tr..4tr+3
    const int tc = t & 15;          // 0..15: output cols 4tc..4tc+3
    const int lr = t >> 4;          // load: row within 16-row group
    const int lc = (t & 15) * 4;    // load: col

    float acc[4][4] = {{0.f}};
    float csum[4] = {0.f, 0.f, 0.f, 0.f};

    float4 kk[4], vv[4];
    // prefetch half 0 (64 rows)
    #pragma unroll
    for (int i = 0; i < 4; ++i) {
        kk[i] = *(const float4*)(Kb + (size_t)(i * 16 + lr) * DIM + lc);
        vv[i] = *(const float4*)(Vb + (size_t)(i * 16 + lr) * DIM + lc);
    }

    #pragma unroll
    for (int half = 0; half < 2; ++half) {
        // elu + per-thread column-sum partial on registers
        #pragma unroll
        for (int i = 0; i < 4; ++i) {
            kk[i].x = elu1(kk[i].x); kk[i].y = elu1(kk[i].y);
            kk[i].z = elu1(kk[i].z); kk[i].w = elu1(kk[i].w);
            csum[0] += kk[i].x; csum[1] += kk[i].y;
            csum[2] += kk[i].z; csum[3] += kk[i].w;
        }
        if (half) __syncthreads();  // prev half's compute must finish before overwrite
        #pragma unroll
        for (int i = 0; i < 4; ++i) {
            *(float4*)&kS[i * 16 + lr][lc] = kk[i];
            *(float4*)&vS[i * 16 + lr][lc] = vv[i];
        }
        __syncthreads();
        if (half == 0) {
            // prefetch half 1 while computing half 0
            #pragma unroll
            for (int i = 0; i < 4; ++i) {
                kk[i] = *(const float4*)(Kb + (size_t)(64 + i * 16 + lr) * DIM + lc);
                vv[i] = *(const float4*)(Vb + (size_t)(64 + i * 16 + lr) * DIM + lc);
            }
        }
        // outer-product accumulation over 64 staged rows
        #pragma unroll 8
        for (int s = 0; s < 64; ++s) {
            const float4 ka = *(const float4*)&kS[s][tr * 4];
            const float4 va = *(const float4*)&vS[s][tc * 4];
            acc[0][0] += ka.x * va.x; acc[0][1] += ka.x * va.y;
            acc[0][2] += ka.x * va.z; acc[0][3] += ka.x * va.w;
            acc[1][0] += ka.y * va.x; acc[1][1] += ka.y * va.y;
            acc[1][2] += ka.y * va.z; acc[1][3] += ka.y * va.w;
            acc[2][0] += ka.z * va.x; acc[2][1] += ka.z * va.y;
            acc[2][2] += ka.z * va.z; acc[2][3] += ka.z * va.w;
            acc[3][0] += ka.w * va.x; acc[3][1] += ka.w * va.y;
            acc[3][2] += ka.w * va.z; acc[3][3] += ka.w * va.w;
        }
    }

    __syncthreads();
    // ksum reduction: thread t holds partial colsum for cols (t&15)*4..+3 over rows
    // {i*16 + t>>4}; the 16 threads sharing (t&15) cover all 128 rows. Reuse kS.
    float* csumS = &kS[0][0];  // [16][64]
    {
        float4 cs;
        cs.x = csum[0]; cs.y = csum[1]; cs.z = csum[2]; cs.w = csum[3];
        *(float4*)&csumS[(size_t)(t >> 4) * 64 + (t & 15) * 4] = cs;
    }
    __syncthreads();
    float ksum = 0.f;
    if (t < DIM) {
        #pragma unroll
        for (int g = 0; g < 16; ++g) ksum += csumS[(size_t)g * 64 + t];
    }

    if (ATOMIC) {
        float* w = dst + (size_t)bh * KVELEM;
        #pragma unroll
        for (int i = 0; i < 4; ++i)
            #pragma unroll
            for (int j = 0; j < 4; ++j)
                atomicAdd(&w[(size_t)(tr * 4 + i) * DIM + tc * 4 + j], acc[i][j]);
        if (t < DIM) atomicAdd(&w[DIM * DIM + t], ksum);
    } else {
        float* w = dst + ((size_t)chunk * BH + bh) * KVELEM;
        #pragma unroll
        for (int i = 0; i < 4; ++i) {
            float4 o;
            o.x = acc[i][0]; o.y = acc[i][1]; o.z = acc[i][2]; o.w = acc[i][3];
            *(float4*)&w[(size_t)(tr * 4 + i) * DIM + tc * 4] = o;
        }
        if (t < DIM) w[DIM * DIM + t] = ksum;
    }
}

__global__ __launch_bounds__(256) void reduce_partials_kernel(
    const float* __restrict__ partial, float* __restrict__ fin) {
    const int bh = blockIdx.y;
    const int j = blockIdx.x * 256 + threadIdx.x;
    if (j >= KVELEM) return;
    float s = 0.f;
    #pragma unroll
    for (int c = 0; c < NCHUNK2; ++c)
        s += partial[((size_t)c * BH + bh) * KVELEM + j];
    fin[(size_t)bh * KVELEM + j] = s;
}

__global__ __launch_bounds__(256) void out_kernel(
    const float* __restrict__ Q, const float* __restrict__ ws,
    float* __restrict__ out) {
    const int bh = blockIdx.y;
    const int rb = blockIdx.x;  // 64-row block
    const float* Qb = Q + ((size_t)bh * SEQ + (size_t)rb * 64) * DIM;
    float* Ob = out + ((size_t)bh * SEQ + (size_t)rb * 64) * DIM;
    const float* w = ws + (size_t)bh * KVELEM;

    // qT2[d][swizzled row]: q'[row][d] at [d][(chunk^(d&15))*4 + (row&3)], chunk=row>>2.
    __shared__ float qT2[DIM][DIM];
    __shared__ float kvS[DIM][DIM];
    __shared__ float ksumS[DIM];
    __shared__ float denomS[64];

    const int t = threadIdx.x;
    const int tr = t >> 4;
    const int tc = t & 15;

    #pragma unroll
    for (int i = 0; i < 4; ++i) {
        const int idx = (i * 256 + t) * 4;
        *(float4*)&kvS[idx >> 6][idx & 63] = *(const float4*)(w + idx);
    }
    if (t < DIM) ksumS[t] = w[DIM * DIM + t];

    {
        const int r0 = tr * 4, c0 = tc * 4;
        float4 ql[4];
        #pragma unroll
        for (int i = 0; i < 4; ++i) {
            float4 qq = *(const float4*)(Qb + (size_t)(r0 + i) * DIM + c0);
            qq.x = elu1(qq.x); qq.y = elu1(qq.y);
            qq.z = elu1(qq.z); qq.w = elu1(qq.w);
            ql[i] = qq;
        }
        #pragma unroll
        for (int j = 0; j < 4; ++j) {
            const int d = c0 + j;
            float4 col;
            col.x = (&ql[0].x)[j]; col.y = (&ql[1].x)[j];
            col.z = (&ql[2].x)[j]; col.w = (&ql[3].x)[j];
            *(float4*)&qT2[d][(tr ^ (d & 15)) * 4] = col;
        }
    }
    __syncthreads();

    if (t < 64) {
        const int chk = t >> 2, lo = t & 3;
        float dsum = 0.f;
        #pragma unroll
        for (int d = 0; d < DIM; ++d) {
            dsum += qT2[d][(chk ^ (d & 15)) * 4 + lo] * ksumS[d];
        }
        denomS[t] = dsum + EPS_LA;
    }

    float acc[4][4] = {{0.f}};
    #pragma unroll
    for (int d = 0; d < DIM; ++d) {
        const float4 qv = *(const float4*)&qT2[d][(tr ^ (d & 15)) * 4];
        const float4 kv = *(const float4*)&kvS[d][tc * 4];
        acc[0][0] += qv.x * kv.x; acc[0][1] += qv.x * kv.y;
        acc[0][2] += qv.x * kv.z; acc[0][3] += qv.x * kv.w;
        acc[1][0] += qv.y * kv.x; acc[1][1] += qv.y * kv.y;
        acc[1][2] += qv.y * kv.z; acc[1][3] += qv.y * kv.w;
        acc[2][0] += qv.z * kv.x; acc[2][1] += qv.z * kv.y;
        acc[2][2] += qv.z * kv.z; acc[2][3] += qv.z * kv.w;
        acc[3][0] += qv.w * kv.x; acc[3][1] += qv.w * kv.y;
        acc[3][2] += qv.w * kv.z; acc[3][3] += qv.w * kv.w;
    }
    __syncthreads();

    #pragma unroll
    for (int i = 0; i < 4; ++i) {
        const float inv = 1.f / denomS[tr * 4 + i];
        float4 o;
        o.x = acc[i][0] * inv; o.y = acc[i][1] * inv;
        o.z = acc[i][2] * inv; o.w = acc[i][3] * inv;
        *(float4*)(Ob + (size_t)(tr * 4 + i) * DIM + tc * 4) = o;
    }
}

extern "C" void kernel_launch(void* const* d_in, const int* in_sizes, int n_in,
                              void* d_out, int out_size, void* d_ws, size_t ws_size,
                              hipStream_t stream) {
    const float* q = (const float*)d_in[0];
    const float* k = (const float*)d_in[1];
    const float* v = (const float*)d_in[2];
    float* out = (float*)d_out;
    float* ws = (float*)d_ws;

    const size_t partial_elems = (size_t)NCHUNK2 * BH * KVELEM;
    const size_t need = (partial_elems + (size_t)BH * KVELEM) * sizeof(float);

    dim3 blk(256);
    if (ws_size >= need) {
        // no-atomic path: partials + reduce (everything fully overwritten each call)
        float* partial = ws;
        float* fin = ws + partial_elems;
        dim3 g1(NCHUNK2, BH);
        hipLaunchKernelGGL(kv_reduce2_kernel<false>, g1, blk, 0, stream, k, v, partial);
        dim3 gr((KVELEM + 255) / 256, BH);
        hipLaunchKernelGGL(reduce_partials_kernel, gr, blk, 0, stream, partial, fin);
        dim3 g2(SEQ / 64, BH);
        hipLaunchKernelGGL(out_kernel, g2, blk, 0, stream, q, fin, out);
    } else {
        // fallback: atomic accumulation
        float* fin = ws;
        hipMemsetAsync(fin, 0, (size_t)BH * KVELEM * sizeof(float), stream);
        dim3 g1(NCHUNK2, BH);
        hipLaunchKernelGGL(kv_reduce2_kernel<true>, g1, blk, 0, stream, k, v, fin);
        dim3 g2(SEQ / 64, BH);
        hipLaunchKernelGGL(out_kernel, g2, blk, 0, stream, q, fin, out);
    }
}